// Round 3
// baseline (792.570 us; speedup 1.0000x reference)
//
#include <hip/hip_runtime.h>
#include <hip/hip_bf16.h>

// MoE forward, MI355X. B=4,S=2048,H=1024,E=8,F=4096,K=2.
// router (no atomics) -> slots (scan + exact offsets + 256-row tile table) ->
// gather x->bf16 -> grouped MFMA GEMM1 (+gelu) -> grouped GEMM2 (+b2) ->
// combine (p0*(y1+y2)).
// GEMM core (m201-style): BM=BN=256, BK=32, 512 thr = 8 waves (2Mx4N), each
// wave owns 128x64 (8x4 frags of 16x16x32) => LDS read B/FLOP 0.023 (vs 0.031
// at 64x64 waves). 4-buffer LDS ring (4x32KB=128KB), staged 3 K-steps ahead
// via global_load_lds; steady-state s_waitcnt vmcnt(8) (never 0); raw
// s_barrier; setprio(1) around each 16-MFMA cluster; 2 phases per K-step.
// LDS pack: 2 global rows per 128B LDS row, XOR swizzle W^=(p&7)<<4 (2-way
// max = free); global source pre-applies inverse XOR (both-sides rule).
// Expert segments UNPADDED (exact cumsum); tiles may overhang into the next
// expert's rows -> compute garbage, mask stores at gm < rowEnd.
// Workspace (bytes), total ~305 MB (fits prior 312.6 MB footprint):
//   [0,384)    meta ints: off[0..8], ntiles@[10], tileInfo[72]@[16..87]
//   [4096,..)  e01[8192] | [36864,..) p0[8192]
//   [69632,..) slot1 | [102400,..) slot2
//   [135168,..)    Xg bf16 [16640][1024] (reused as ybuf)
//   [34213888,..)  W1t bf16 [8][4096][1024]
//   [101322752,..) W2t bf16 [8][1024][4096]
//   [168431616,..) h  bf16 [16640][4096]  (ends 304746496)

typedef __bf16 bf16;
typedef __attribute__((ext_vector_type(4))) __bf16 bf16x4;
typedef __attribute__((ext_vector_type(8))) __bf16 bf16x8;
typedef __attribute__((ext_vector_type(4))) float f32x4;

#define GLD16(g, l) __builtin_amdgcn_global_load_lds( \
    (__attribute__((address_space(1))) void*)(g),      \
    (__attribute__((address_space(3))) void*)(l), 16, 0, 0)

// gelu tanh-approx == v * sigmoid(2c), 2c = 1.5957691216*v + 0.07135481627*v^3.
__device__ __forceinline__ float gelu_fast(float v) {
  float u = v * fmaf(v * v, 0.0713548162726f, 1.5957691216057308f);
  return v * __builtin_amdgcn_rcpf(1.0f + __expf(-u));
}

// ---------------- router: 1 wave per token, no atomics ----------------
__global__ __launch_bounds__(256) void router_kernel(
    const float* __restrict__ x, const float* __restrict__ Wr,
    const float* __restrict__ br, int* __restrict__ e01,
    float* __restrict__ p0arr) {
  int wv = threadIdx.x >> 6;
  int l = threadIdx.x & 63;
  int t = blockIdx.x * 4 + wv;
  float acc[8];
#pragma unroll
  for (int e = 0; e < 8; e++) acc[e] = 0.f;
  const float* xr = x + (size_t)t * 1024;
#pragma unroll
  for (int i = 0; i < 16; i++) {
    int h = l + i * 64;
    float xv = xr[h];
    const float4* w4 = (const float4*)(Wr + h * 8);
    float4 wa = w4[0], wb = w4[1];
    acc[0] += xv * wa.x; acc[1] += xv * wa.y; acc[2] += xv * wa.z; acc[3] += xv * wa.w;
    acc[4] += xv * wb.x; acc[5] += xv * wb.y; acc[6] += xv * wb.z; acc[7] += xv * wb.w;
  }
#pragma unroll
  for (int e = 0; e < 8; e++) {
    float v = acc[e];
#pragma unroll
    for (int m = 1; m < 64; m <<= 1) v += __shfl_xor(v, m, 64);
    acc[e] = v + br[e];
  }
  int i1 = 0; float m1 = acc[0];
#pragma unroll
  for (int e = 1; e < 8; e++) { if (acc[e] > m1) { m1 = acc[e]; i1 = e; } }
  int i2 = -1; float m2 = -3.4e38f;
#pragma unroll
  for (int e = 0; e < 8; e++) { if (e != i1 && acc[e] > m2) { m2 = acc[e]; i2 = e; } }
  if (l == 0) {
    e01[t] = i1 | (i2 << 8);
    p0arr[t] = 1.0f / (1.0f + __expf(m2 - m1));  // normalized top-1 prob
  }
}

// ---------------- slots: counts + exact offsets + slots + tile table --------
__global__ __launch_bounds__(1024) void slots_kernel(
    const int* __restrict__ e01, int* __restrict__ meta,
    int* __restrict__ slot1, int* __restrict__ slot2) {
  __shared__ int wtot[16];
  int tid = threadIdx.x;
  int l = tid & 63, wv = tid >> 6;
  int t0 = tid * 8;
  int i1[8], i2[8];
#pragma unroll
  for (int i = 0; i < 8; i++) {
    int ee = e01[t0 + i];
    i1[i] = ee & 255;
    i2[i] = (ee >> 8) & 255;
  }
  int offl[9];
  int running = 0;  // exact cumulative offset (identical in all threads)
  for (int e = 0; e < 8; e++) {
    offl[e] = running;
    int cthread = 0;
#pragma unroll
    for (int i = 0; i < 8; i++) cthread += (i1[i] == e) + (i2[i] == e);
    int inc = cthread;
#pragma unroll
    for (int d = 1; d < 64; d <<= 1) {
      int v = __shfl_up(inc, d, 64);
      if (l >= d) inc += v;
    }
    if (l == 63) wtot[wv] = inc;
    __syncthreads();
    int wbase = 0, total = 0;
#pragma unroll
    for (int w = 0; w < 16; w++) {
      int tw = wtot[w];
      wbase += (w < wv) ? tw : 0;
      total += tw;
    }
    int base = running + wbase + (inc - cthread);
#pragma unroll
    for (int i = 0; i < 8; i++) {
      if (i1[i] == e) { slot1[t0 + i] = base; base++; }
      if (i2[i] == e) { slot2[t0 + i] = base; base++; }
    }
    running += total;
    __syncthreads();  // protect wtot for next pass
  }
  offl[8] = running;
  if (tid == 0) {
#pragma unroll
    for (int e = 0; e < 9; e++) meta[e] = offl[e];
    int nt = 0;
    for (int e = 0; e < 8; e++)
      for (int r = offl[e]; r < offl[e + 1]; r += 256)
        meta[16 + (nt++)] = r | (e << 20);
    meta[10] = nt;
  }
}

// ---------------- gather: x -> bf16 into both expert slots ----------------
__global__ __launch_bounds__(256) void gather_kernel(
    const float* __restrict__ x, const int* __restrict__ slot1,
    const int* __restrict__ slot2, bf16* __restrict__ Xg) {
  int t = blockIdx.x;
  int s1 = slot1[t], s2 = slot2[t];
  float4 v = ((const float4*)(x + (size_t)t * 1024))[threadIdx.x];
  bf16x4 bv = { (bf16)v.x, (bf16)v.y, (bf16)v.z, (bf16)v.w };
  *(bf16x4*)(Xg + (size_t)s1 * 1024 + threadIdx.x * 4) = bv;
  *(bf16x4*)(Xg + (size_t)s2 * 1024 + threadIdx.x * 4) = bv;
}

// ---------------- transpose + fp32->bf16: in [E][R][C] -> out [E][C][R] ----
__global__ __launch_bounds__(256) void tconv_kernel(
    const float* __restrict__ in, bf16* __restrict__ out, int R, int C) {
  __shared__ float tile[64][65];
  size_t base = (size_t)blockIdx.z * R * C;
  int gr0 = blockIdx.y * 64, gc0 = blockIdx.x * 64;
#pragma unroll
  for (int i = 0; i < 16; i++) {
    int idx = threadIdx.x + i * 256;
    int r = idx >> 6, c = idx & 63;
    tile[r][c] = in[base + (size_t)(gr0 + r) * C + gc0 + c];
  }
  __syncthreads();
  int rr0 = (threadIdx.x & 15) * 4;
#pragma unroll
  for (int i = 0; i < 4; i++) {
    int cc = (threadIdx.x >> 4) + i * 16;
    bf16x4 v = { (bf16)tile[rr0][cc], (bf16)tile[rr0 + 1][cc],
                 (bf16)tile[rr0 + 2][cc], (bf16)tile[rr0 + 3][cc] };
    *(bf16x4*)&out[base + (size_t)(gc0 + cc) * R + gr0 + rr0] = v;
  }
}

// ================= GEMM core (BM=BN=256, BK=32, 4-buffer ring) =============
// A [M][K], B [N][K], bf16 K-contig. Buffer (32KB): A 16KB @0, B 16KB @16384.
// Pack: global row r -> LDS row p=r>>1 (128B); within-row logical offset
// L = ((r&1)<<6)|c  stored at W = L ^ ((p&7)<<4). Staging inverts the XOR on
// the global source so linear global_load_lds lands correct.
// Per K-step: ph0 {read B0..3 + A0..3, stage 2, barrier, lgkm0, 16 MFMA,
// barrier}; ph1 {read A4..7, stage 2, barrier, lgkm0, 16 MFMA, vmcnt(8),
// barrier}. 3 steps in flight => vmcnt(8) steady state.
__device__ __forceinline__ void gemm256_core(
    const bf16* __restrict__ Abase, const bf16* __restrict__ Bbase,
    int K, int NT, char* smem, f32x4 acc[8][4], int wr, int wc, int l) {
  int tid = threadIdx.x;
  size_t K2 = (size_t)K * 2;  // row stride bytes
  const char* src[4];
  int dst[4];
#pragma unroll
  for (int i = 0; i < 4; i++) {
    int s = (i & 1) ? (tid + 512) : tid;
    int byteoff = s * 16;
    int p = byteoff >> 7;
    int W = byteoff & 127;
    int L = W ^ ((p & 7) << 4);
    int r = 2 * p + (L >> 6);
    int c = L & 63;
    const char* base = (const char*)((i >= 2) ? Bbase : Abase);
    src[i] = base + (size_t)r * K2 + c;
    dst[i] = ((i >= 2) ? 16384 : 0) + byteoff;
  }
  int offA[8], offB[4];
  int kc16 = (l >> 4) << 4;
#pragma unroll
  for (int mf = 0; mf < 8; mf++) {
    int r = wr * 128 + mf * 16 + (l & 15);
    int p = r >> 1;
    offA[mf] = (p << 7) + ((((r & 1) << 6) | kc16) ^ ((p & 7) << 4));
  }
#pragma unroll
  for (int nf = 0; nf < 4; nf++) {
    int r = wc * 64 + nf * 16 + (l & 15);
    int p = r >> 1;
    offB[nf] = 16384 + (p << 7) + ((((r & 1) << 6) | kc16) ^ ((p & 7) << 4));
  }
  // prologue: stage K-steps 0,1,2 into bufs 0,1,2 (12 loads in flight)
#pragma unroll
  for (int t = 0; t < 3; t++) {
    char* bu = smem + t * 32768;
#pragma unroll
    for (int i = 0; i < 4; i++) GLD16(src[i] + t * 64, bu + dst[i]);
  }
  asm volatile("s_waitcnt vmcnt(8)" ::: "memory");  // step 0 resident
  __builtin_amdgcn_s_barrier();
  for (int t = 0; t < NT; t++) {
    char* bc = smem + (t & 3) * 32768;
    char* bs = smem + ((t + 3) & 3) * 32768;
    bool st = (t + 3) < NT;
    bf16x8 bfr[4], af[4];
    // ---- phase 0 ----
#pragma unroll
    for (int nf = 0; nf < 4; nf++) bfr[nf] = *(const bf16x8*)(bc + offB[nf]);
#pragma unroll
    for (int mf = 0; mf < 4; mf++) af[mf] = *(const bf16x8*)(bc + offA[mf]);
    if (st) {
      GLD16(src[0] + (t + 3) * 64, bs + dst[0]);
      GLD16(src[1] + (t + 3) * 64, bs + dst[1]);
    }
    __builtin_amdgcn_s_barrier();
    asm volatile("s_waitcnt lgkmcnt(0)" ::: "memory");
    __builtin_amdgcn_s_setprio(1);
#pragma unroll
    for (int mf = 0; mf < 4; mf++)
#pragma unroll
      for (int nf = 0; nf < 4; nf++)
        acc[mf][nf] = __builtin_amdgcn_mfma_f32_16x16x32_bf16(bfr[nf], af[mf], acc[mf][nf], 0, 0, 0);
    __builtin_amdgcn_s_setprio(0);
    __builtin_amdgcn_s_barrier();
    // ---- phase 1 ----
#pragma unroll
    for (int mf = 0; mf < 4; mf++) af[mf] = *(const bf16x8*)(bc + offA[mf + 4]);
    if (st) {
      GLD16(src[2] + (t + 3) * 64, bs + dst[2]);
      GLD16(src[3] + (t + 3) * 64, bs + dst[3]);
    }
    __builtin_amdgcn_s_barrier();
    asm volatile("s_waitcnt lgkmcnt(0)" ::: "memory");
    __builtin_amdgcn_s_setprio(1);
#pragma unroll
    for (int mf = 0; mf < 4; mf++)
#pragma unroll
      for (int nf = 0; nf < 4; nf++)
        acc[mf + 4][nf] = __builtin_amdgcn_mfma_f32_16x16x32_bf16(bfr[nf], af[mf], acc[mf + 4][nf], 0, 0, 0);
    __builtin_amdgcn_s_setprio(0);
    if ((t + 3) < NT)      { asm volatile("s_waitcnt vmcnt(8)" ::: "memory"); }
    else if ((t + 2) < NT) { asm volatile("s_waitcnt vmcnt(4)" ::: "memory"); }
    else if ((t + 1) < NT) { asm volatile("s_waitcnt vmcnt(0)" ::: "memory"); }
    __builtin_amdgcn_s_barrier();
  }
}

// ---------------- grouped GEMM1: h = gelu(Xg @ W1[e] + b1[e]) ----------------
// Grid 1152: xcd=b&7, j=b>>3 (0..143); m_idx=(j>>4)*8+xcd, n_tile=j&15.
__global__ __launch_bounds__(512, 2) void gemm1_kernel(
    const bf16* __restrict__ Xg, const bf16* __restrict__ W1t,
    const float* __restrict__ b1, bf16* __restrict__ hbuf,
    const int* __restrict__ meta) {
  __shared__ __align__(16) char smem[131072];
  int b = blockIdx.x;
  int xcd = b & 7, j = b >> 3;
  int m_idx = (j >> 4) * 8 + xcd;
  int n_tile = j & 15;
  if (m_idx >= meta[10]) return;
  int ti = meta[16 + m_idx];
  int row0 = ti & 0xFFFFF;
  int e = ti >> 20;
  int rowEnd = meta[1 + e];
  int tid = threadIdx.x;
  int w = tid >> 6, l = tid & 63;
  int wr = w >> 2, wc = w & 3;
  f32x4 acc[8][4];
#pragma unroll
  for (int a = 0; a < 8; a++)
#pragma unroll
    for (int bb = 0; bb < 4; bb++) acc[a][bb] = (f32x4){0.f, 0.f, 0.f, 0.f};
  gemm256_core(Xg + (size_t)row0 * 1024,
               W1t + ((size_t)e * 4096 + n_tile * 256) * 1024,
               1024, 32, smem, acc, wr, wc, l);
  int mrow = l & 15, nq = (l >> 4) * 4;
  int gn0 = n_tile * 256 + wc * 64 + nq;
  f32x4 bv[4];
#pragma unroll
  for (int nf = 0; nf < 4; nf++)
    bv[nf] = *(const f32x4*)(b1 + e * 4096 + gn0 + nf * 16);
#pragma unroll
  for (int mf = 0; mf < 8; mf++) {
    int gm = row0 + wr * 128 + mf * 16 + mrow;
    if (gm < rowEnd) {
      bf16* rp = hbuf + (size_t)gm * 4096 + gn0;
#pragma unroll
      for (int nf = 0; nf < 4; nf++) {
        bf16x4 o;
#pragma unroll
        for (int jj = 0; jj < 4; jj++)
          o[jj] = (bf16)gelu_fast(acc[mf][nf][jj] + bv[nf][jj]);
        *(bf16x4*)(rp + nf * 16) = o;
      }
    }
  }
}

// ---------------- grouped GEMM2: y[slot] = h @ W2[e] + b2[e] (bf16) ---------
// Grid 288: xcd=b&7, j=b>>3 (0..35); m_idx=(j>>2)*8+xcd, n_tile=j&3.
__global__ __launch_bounds__(512, 2) void gemm2_kernel(
    const bf16* __restrict__ hbuf, const bf16* __restrict__ W2t,
    const float* __restrict__ b2, bf16* __restrict__ yb,
    const int* __restrict__ meta) {
  __shared__ __align__(16) char smem[131072];
  int b = blockIdx.x;
  int xcd = b & 7, j = b >> 3;
  int m_idx = (j >> 2) * 8 + xcd;
  int n_tile = j & 3;
  if (m_idx >= meta[10]) return;
  int ti = meta[16 + m_idx];
  int row0 = ti & 0xFFFFF;
  int e = ti >> 20;
  int rowEnd = meta[1 + e];
  int tid = threadIdx.x;
  int w = tid >> 6, l = tid & 63;
  int wr = w >> 2, wc = w & 3;
  f32x4 acc[8][4];
#pragma unroll
  for (int a = 0; a < 8; a++)
#pragma unroll
    for (int bb = 0; bb < 4; bb++) acc[a][bb] = (f32x4){0.f, 0.f, 0.f, 0.f};
  gemm256_core(hbuf + (size_t)row0 * 4096,
               W2t + ((size_t)e * 1024 + n_tile * 256) * 4096,
               4096, 128, smem, acc, wr, wc, l);
  int mrow = l & 15, nq = (l >> 4) * 4;
  int gn0 = n_tile * 256 + wc * 64 + nq;
  f32x4 bv[4];
#pragma unroll
  for (int nf = 0; nf < 4; nf++)
    bv[nf] = *(const f32x4*)(b2 + e * 1024 + gn0 + nf * 16);
#pragma unroll
  for (int mf = 0; mf < 8; mf++) {
    int gm = row0 + wr * 128 + mf * 16 + mrow;
    if (gm < rowEnd) {
      bf16* rp = yb + (size_t)gm * 1024 + gn0;
#pragma unroll
      for (int nf = 0; nf < 4; nf++) {
        bf16x4 o;
#pragma unroll
        for (int jj = 0; jj < 4; jj++)
          o[jj] = (bf16)(acc[mf][nf][jj] + bv[nf][jj]);
        *(bf16x4*)(rp + nf * 16) = o;
      }
    }
  }
}

// ---------------- combine: out[t] = p0[t] * (y[s1] + y[s2]) -----------------
__global__ __launch_bounds__(256) void combine_kernel(
    const bf16* __restrict__ yb, const int* __restrict__ slot1,
    const int* __restrict__ slot2, const float* __restrict__ p0arr,
    float* __restrict__ out) {
  int t = blockIdx.x;
  int s1 = slot1[t], s2 = slot2[t];
  float w0 = p0arr[t];
  bf16x4 a = *(const bf16x4*)(yb + (size_t)s1 * 1024 + threadIdx.x * 4);
  bf16x4 b = *(const bf16x4*)(yb + (size_t)s2 * 1024 + threadIdx.x * 4);
  float4 o;
  o.x = w0 * ((float)a[0] + (float)b[0]);
  o.y = w0 * ((float)a[1] + (float)b[1]);
  o.z = w0 * ((float)a[2] + (float)b[2]);
  o.w = w0 * ((float)a[3] + (float)b[3]);
  *(float4*)(out + (size_t)t * 1024 + threadIdx.x * 4) = o;
}

extern "C" void kernel_launch(void* const* d_in, const int* in_sizes, int n_in,
                              void* d_out, int out_size, void* d_ws, size_t ws_size,
                              hipStream_t stream) {
  const float* x  = (const float*)d_in[0];
  const float* Wr = (const float*)d_in[1];
  const float* br = (const float*)d_in[2];
  const float* W1 = (const float*)d_in[3];
  const float* b1 = (const float*)d_in[4];
  const float* W2 = (const float*)d_in[5];
  const float* b2 = (const float*)d_in[6];
  float* out = (float*)d_out;

  char* ws = (char*)d_ws;
  int*   meta  = (int*)(ws + 0);
  int*   e01   = (int*)(ws + 4096);
  float* p0    = (float*)(ws + 36864);
  int*   slot1 = (int*)(ws + 69632);
  int*   slot2 = (int*)(ws + 102400);
  bf16*  Xg    = (bf16*)(ws + 135168);          // reused as ybuf after gemm1
  bf16*  W1t   = (bf16*)(ws + 34213888ULL);
  bf16*  W2t   = (bf16*)(ws + 101322752ULL);
  bf16*  hb    = (bf16*)(ws + 168431616ULL);
  bf16*  yb    = Xg;

  tconv_kernel<<<dim3(64, 16, 8), 256, 0, stream>>>(W1, W1t, 1024, 4096);
  tconv_kernel<<<dim3(16, 64, 8), 256, 0, stream>>>(W2, W2t, 4096, 1024);
  router_kernel<<<2048, 256, 0, stream>>>(x, Wr, br, e01, p0);
  slots_kernel<<<1, 1024, 0, stream>>>(e01, meta, slot1, slot2);
  gather_kernel<<<8192, 256, 0, stream>>>(x, slot1, slot2, Xg);
  gemm1_kernel<<<1152, 512, 0, stream>>>(Xg, W1t, b1, hb, meta);
  gemm2_kernel<<<288, 512, 0, stream>>>(hb, W2t, b2, yb, meta);
  combine_kernel<<<8192, 256, 0, stream>>>(yb, slot1, slot2, p0, out);
}

// Round 4
// 789.031 us; speedup vs baseline: 1.0045x; 1.0045x over previous
//
#include <hip/hip_runtime.h>
#include <hip/hip_bf16.h>

// MoE forward, MI355X. B=4,S=2048,H=1024,E=8,F=4096,K=2.
// router (no atomics) -> slots (scan + exact offsets + 256-row tile table) ->
// gather x->bf16 -> grouped MFMA GEMM1 (+gelu) -> grouped GEMM2 (+b2) ->
// combine (p0*(y1+y2)).
// GEMM core (m201-style): BM=BN=256, BK=32, 512 thr = 8 waves (2Mx4N), each
// wave owns 128x64 (8x4 frags of 16x16x32). 4-buffer LDS ring (4x32KB=128KB),
// staged 3 K-steps ahead via global_load_lds; steady-state vmcnt(8) (never 0);
// raw s_barrier; setprio(1) around MFMA clusters; 2 phases per K-step.
// Tile->block map: bijective chunked XCD split (contiguous tidx range per XCD,
// n fastest) => co-resident same-XCD blocks share A panels (xN) and B panels
// (xM within expert) at K-strip granularity in L2. (R3's interleaved map had
// zero same-XCD B sharing -> FETCH doubled.)
// LDS pack: 2 global rows per 128B LDS row, XOR swizzle W^=(p&7)<<4; global
// source pre-applies inverse XOR (both-sides rule).
// Expert segments UNPADDED; tiles may overhang -> mask stores at gm < rowEnd.
// Workspace (bytes), total ~305 MB:
//   [0,384)    meta ints: off[0..8], ntiles@[10], tileInfo[72]@[16..87]
//   [4096,..)  e01[8192] | [36864,..) p0[8192]
//   [69632,..) slot1 | [102400,..) slot2
//   [135168,..)    Xg bf16 [16640][1024] (reused as ybuf)
//   [34213888,..)  W1t bf16 [8][4096][1024]
//   [101322752,..) W2t bf16 [8][1024][4096]
//   [168431616,..) h  bf16 [16640][4096]  (ends 304746496)

typedef __bf16 bf16;
typedef __attribute__((ext_vector_type(4))) __bf16 bf16x4;
typedef __attribute__((ext_vector_type(8))) __bf16 bf16x8;
typedef __attribute__((ext_vector_type(4))) float f32x4;

#define GLD16(g, l) __builtin_amdgcn_global_load_lds( \
    (__attribute__((address_space(1))) void*)(g),      \
    (__attribute__((address_space(3))) void*)(l), 16, 0, 0)

// gelu tanh-approx == v * sigmoid(2c), 2c = 1.5957691216*v + 0.07135481627*v^3.
__device__ __forceinline__ float gelu_fast(float v) {
  float u = v * fmaf(v * v, 0.0713548162726f, 1.5957691216057308f);
  return v * __builtin_amdgcn_rcpf(1.0f + __expf(-u));
}

// ---------------- router: 1 wave per token, no atomics ----------------
__global__ __launch_bounds__(256) void router_kernel(
    const float* __restrict__ x, const float* __restrict__ Wr,
    const float* __restrict__ br, int* __restrict__ e01,
    float* __restrict__ p0arr) {
  int wv = threadIdx.x >> 6;
  int l = threadIdx.x & 63;
  int t = blockIdx.x * 4 + wv;
  float acc[8];
#pragma unroll
  for (int e = 0; e < 8; e++) acc[e] = 0.f;
  const float* xr = x + (size_t)t * 1024;
#pragma unroll
  for (int i = 0; i < 16; i++) {
    int h = l + i * 64;
    float xv = xr[h];
    const float4* w4 = (const float4*)(Wr + h * 8);
    float4 wa = w4[0], wb = w4[1];
    acc[0] += xv * wa.x; acc[1] += xv * wa.y; acc[2] += xv * wa.z; acc[3] += xv * wa.w;
    acc[4] += xv * wb.x; acc[5] += xv * wb.y; acc[6] += xv * wb.z; acc[7] += xv * wb.w;
  }
#pragma unroll
  for (int e = 0; e < 8; e++) {
    float v = acc[e];
#pragma unroll
    for (int m = 1; m < 64; m <<= 1) v += __shfl_xor(v, m, 64);
    acc[e] = v + br[e];
  }
  int i1 = 0; float m1 = acc[0];
#pragma unroll
  for (int e = 1; e < 8; e++) { if (acc[e] > m1) { m1 = acc[e]; i1 = e; } }
  int i2 = -1; float m2 = -3.4e38f;
#pragma unroll
  for (int e = 0; e < 8; e++) { if (e != i1 && acc[e] > m2) { m2 = acc[e]; i2 = e; } }
  if (l == 0) {
    e01[t] = i1 | (i2 << 8);
    p0arr[t] = 1.0f / (1.0f + __expf(m2 - m1));  // normalized top-1 prob
  }
}

// ---------------- slots: counts + exact offsets + slots + tile table --------
__global__ __launch_bounds__(1024) void slots_kernel(
    const int* __restrict__ e01, int* __restrict__ meta,
    int* __restrict__ slot1, int* __restrict__ slot2) {
  __shared__ int wtot[16];
  int tid = threadIdx.x;
  int l = tid & 63, wv = tid >> 6;
  int t0 = tid * 8;
  int i1[8], i2[8];
#pragma unroll
  for (int i = 0; i < 8; i++) {
    int ee = e01[t0 + i];
    i1[i] = ee & 255;
    i2[i] = (ee >> 8) & 255;
  }
  int offl[9];
  int running = 0;  // exact cumulative offset (identical in all threads)
  for (int e = 0; e < 8; e++) {
    offl[e] = running;
    int cthread = 0;
#pragma unroll
    for (int i = 0; i < 8; i++) cthread += (i1[i] == e) + (i2[i] == e);
    int inc = cthread;
#pragma unroll
    for (int d = 1; d < 64; d <<= 1) {
      int v = __shfl_up(inc, d, 64);
      if (l >= d) inc += v;
    }
    if (l == 63) wtot[wv] = inc;
    __syncthreads();
    int wbase = 0, total = 0;
#pragma unroll
    for (int w = 0; w < 16; w++) {
      int tw = wtot[w];
      wbase += (w < wv) ? tw : 0;
      total += tw;
    }
    int base = running + wbase + (inc - cthread);
#pragma unroll
    for (int i = 0; i < 8; i++) {
      if (i1[i] == e) { slot1[t0 + i] = base; base++; }
      if (i2[i] == e) { slot2[t0 + i] = base; base++; }
    }
    running += total;
    __syncthreads();  // protect wtot for next pass
  }
  offl[8] = running;
  if (tid == 0) {
#pragma unroll
    for (int e = 0; e < 9; e++) meta[e] = offl[e];
    int nt = 0;
    for (int e = 0; e < 8; e++)
      for (int r = offl[e]; r < offl[e + 1]; r += 256)
        meta[16 + (nt++)] = r | (e << 20);
    meta[10] = nt;
  }
}

// ---------------- gather: x -> bf16 into both expert slots ----------------
__global__ __launch_bounds__(256) void gather_kernel(
    const float* __restrict__ x, const int* __restrict__ slot1,
    const int* __restrict__ slot2, bf16* __restrict__ Xg) {
  int t = blockIdx.x;
  int s1 = slot1[t], s2 = slot2[t];
  float4 v = ((const float4*)(x + (size_t)t * 1024))[threadIdx.x];
  bf16x4 bv = { (bf16)v.x, (bf16)v.y, (bf16)v.z, (bf16)v.w };
  *(bf16x4*)(Xg + (size_t)s1 * 1024 + threadIdx.x * 4) = bv;
  *(bf16x4*)(Xg + (size_t)s2 * 1024 + threadIdx.x * 4) = bv;
}

// ---------------- transpose + fp32->bf16: in [E][R][C] -> out [E][C][R] ----
// float4 LDS fills, bf16x8 coalesced stores (16B per lane).
__global__ __launch_bounds__(256) void tconv_kernel(
    const float* __restrict__ in, bf16* __restrict__ out, int R, int C) {
  __shared__ float tile[64][65];
  size_t base = (size_t)blockIdx.z * R * C;
  int gr0 = blockIdx.y * 64, gc0 = blockIdx.x * 64;
  int tr = threadIdx.x >> 4;         // 0..15
  int tc4 = (threadIdx.x & 15) * 4;  // 0..60
#pragma unroll
  for (int i = 0; i < 4; i++) {
    int r = tr + i * 16;
    float4 v = *(const float4*)&in[base + (size_t)(gr0 + r) * C + gc0 + tc4];
    tile[r][tc4] = v.x; tile[r][tc4 + 1] = v.y;
    tile[r][tc4 + 2] = v.z; tile[r][tc4 + 3] = v.w;
  }
  __syncthreads();
  int rr0 = (threadIdx.x & 7) * 8;  // 0..56
  int cc0 = threadIdx.x >> 3;       // 0..31
#pragma unroll
  for (int i = 0; i < 2; i++) {
    int cc = cc0 + i * 32;
    bf16x8 v;
#pragma unroll
    for (int k = 0; k < 8; k++) v[k] = (bf16)tile[rr0 + k][cc];
    *(bf16x8*)&out[base + (size_t)(gc0 + cc) * R + gr0 + rr0] = v;
  }
}

// ---------- bijective chunked XCD tile map (m204 pattern) ----------
// total tiles = ntiles << nshift, flattened tidx = m_idx<<nshift | n (n fastest).
// XCD xcd gets a contiguous tidx chunk -> same-XCD co-resident blocks share
// A panels (consecutive n) and B panels (consecutive m, mostly one expert).
__device__ __forceinline__ bool xcd_tile(int b, int ntiles, int nshift,
                                         int& m_idx, int& n_tile) {
  int xcd = b & 7, j = b >> 3;
  int total = ntiles << nshift;
  int q = total >> 3, r = total & 7;
  int cnt = q + (xcd < r ? 1 : 0);
  if (j >= cnt) return false;
  int start = (xcd < r) ? xcd * (q + 1) : r * (q + 1) + (xcd - r) * q;
  int tidx = start + j;
  m_idx = tidx >> nshift;
  n_tile = tidx & ((1 << nshift) - 1);
  return true;
}

// ================= GEMM core (BM=BN=256, BK=32, 4-buffer ring) =============
// A [M][K], B [N][K], bf16 K-contig. Buffer (32KB): A 16KB @0, B 16KB @16384.
// Pack: global row r -> LDS row p=r>>1 (128B); within-row logical offset
// L = ((r&1)<<6)|c  stored at W = L ^ ((p&7)<<4). Staging inverts the XOR on
// the global source so linear global_load_lds lands correct.
// Per K-step: ph0 {read B0..3 + A0..3, stage 2, barrier, lgkm0, 16 MFMA,
// barrier}; ph1 {read A4..7, stage 2, barrier, lgkm0, 16 MFMA, vmcnt(8),
// barrier}. 3 steps in flight => vmcnt(8) steady state.
__device__ __forceinline__ void gemm256_core(
    const bf16* __restrict__ Abase, const bf16* __restrict__ Bbase,
    int K, int NT, char* smem, f32x4 acc[8][4], int wr, int wc, int l) {
  int tid = threadIdx.x;
  size_t K2 = (size_t)K * 2;  // row stride bytes
  const char* src[4];
  int dst[4];
#pragma unroll
  for (int i = 0; i < 4; i++) {
    int s = (i & 1) ? (tid + 512) : tid;
    int byteoff = s * 16;
    int p = byteoff >> 7;
    int W = byteoff & 127;
    int L = W ^ ((p & 7) << 4);
    int r = 2 * p + (L >> 6);
    int c = L & 63;
    const char* base = (const char*)((i >= 2) ? Bbase : Abase);
    src[i] = base + (size_t)r * K2 + c;
    dst[i] = ((i >= 2) ? 16384 : 0) + byteoff;
  }
  int offA[8], offB[4];
  int kc16 = (l >> 4) << 4;
#pragma unroll
  for (int mf = 0; mf < 8; mf++) {
    int r = wr * 128 + mf * 16 + (l & 15);
    int p = r >> 1;
    offA[mf] = (p << 7) + ((((r & 1) << 6) | kc16) ^ ((p & 7) << 4));
  }
#pragma unroll
  for (int nf = 0; nf < 4; nf++) {
    int r = wc * 64 + nf * 16 + (l & 15);
    int p = r >> 1;
    offB[nf] = 16384 + (p << 7) + ((((r & 1) << 6) | kc16) ^ ((p & 7) << 4));
  }
  // prologue: stage K-steps 0,1,2 into bufs 0,1,2 (12 loads in flight)
#pragma unroll
  for (int t = 0; t < 3; t++) {
    char* bu = smem + t * 32768;
#pragma unroll
    for (int i = 0; i < 4; i++) GLD16(src[i] + t * 64, bu + dst[i]);
  }
  asm volatile("s_waitcnt vmcnt(8)" ::: "memory");  // step 0 resident
  __builtin_amdgcn_s_barrier();
  for (int t = 0; t < NT; t++) {
    char* bc = smem + (t & 3) * 32768;
    char* bs = smem + ((t + 3) & 3) * 32768;
    bool st = (t + 3) < NT;
    bf16x8 bfr[4], af[4];
    // ---- phase 0 ----
#pragma unroll
    for (int nf = 0; nf < 4; nf++) bfr[nf] = *(const bf16x8*)(bc + offB[nf]);
#pragma unroll
    for (int mf = 0; mf < 4; mf++) af[mf] = *(const bf16x8*)(bc + offA[mf]);
    if (st) {
      GLD16(src[0] + (t + 3) * 64, bs + dst[0]);
      GLD16(src[1] + (t + 3) * 64, bs + dst[1]);
    }
    __builtin_amdgcn_s_barrier();
    asm volatile("s_waitcnt lgkmcnt(0)" ::: "memory");
    __builtin_amdgcn_s_setprio(1);
#pragma unroll
    for (int mf = 0; mf < 4; mf++)
#pragma unroll
      for (int nf = 0; nf < 4; nf++)
        acc[mf][nf] = __builtin_amdgcn_mfma_f32_16x16x32_bf16(bfr[nf], af[mf], acc[mf][nf], 0, 0, 0);
    __builtin_amdgcn_s_setprio(0);
    __builtin_amdgcn_s_barrier();
    // ---- phase 1 ----
#pragma unroll
    for (int mf = 0; mf < 4; mf++) af[mf] = *(const bf16x8*)(bc + offA[mf + 4]);
    if (st) {
      GLD16(src[2] + (t + 3) * 64, bs + dst[2]);
      GLD16(src[3] + (t + 3) * 64, bs + dst[3]);
    }
    __builtin_amdgcn_s_barrier();
    asm volatile("s_waitcnt lgkmcnt(0)" ::: "memory");
    __builtin_amdgcn_s_setprio(1);
#pragma unroll
    for (int mf = 0; mf < 4; mf++)
#pragma unroll
      for (int nf = 0; nf < 4; nf++)
        acc[mf + 4][nf] = __builtin_amdgcn_mfma_f32_16x16x32_bf16(bfr[nf], af[mf], acc[mf + 4][nf], 0, 0, 0);
    __builtin_amdgcn_s_setprio(0);
    if ((t + 3) < NT)      { asm volatile("s_waitcnt vmcnt(8)" ::: "memory"); }
    else if ((t + 2) < NT) { asm volatile("s_waitcnt vmcnt(4)" ::: "memory"); }
    else if ((t + 1) < NT) { asm volatile("s_waitcnt vmcnt(0)" ::: "memory"); }
    __builtin_amdgcn_s_barrier();
  }
}

// ---------------- grouped GEMM1: h = gelu(Xg @ W1[e] + b1[e]) ----------------
// Grid 1152 = 8 xcd x 144; chunked-bijective tidx split, 16 n_tiles.
__global__ __launch_bounds__(512, 2) void gemm1_kernel(
    const bf16* __restrict__ Xg, const bf16* __restrict__ W1t,
    const float* __restrict__ b1, bf16* __restrict__ hbuf,
    const int* __restrict__ meta) {
  __shared__ __align__(16) char smem[131072];
  int m_idx, n_tile;
  if (!xcd_tile(blockIdx.x, meta[10], 4, m_idx, n_tile)) return;
  int ti = meta[16 + m_idx];
  int row0 = ti & 0xFFFFF;
  int e = ti >> 20;
  int rowEnd = meta[1 + e];
  int tid = threadIdx.x;
  int w = tid >> 6, l = tid & 63;
  int wr = w >> 2, wc = w & 3;
  f32x4 acc[8][4];
#pragma unroll
  for (int a = 0; a < 8; a++)
#pragma unroll
    for (int bb = 0; bb < 4; bb++) acc[a][bb] = (f32x4){0.f, 0.f, 0.f, 0.f};
  gemm256_core(Xg + (size_t)row0 * 1024,
               W1t + ((size_t)e * 4096 + n_tile * 256) * 1024,
               1024, 32, smem, acc, wr, wc, l);
  int mrow = l & 15, nq = (l >> 4) * 4;
  int gn0 = n_tile * 256 + wc * 64 + nq;
  f32x4 bv[4];
#pragma unroll
  for (int nf = 0; nf < 4; nf++)
    bv[nf] = *(const f32x4*)(b1 + e * 4096 + gn0 + nf * 16);
#pragma unroll
  for (int mf = 0; mf < 8; mf++) {
    int gm = row0 + wr * 128 + mf * 16 + mrow;
    if (gm < rowEnd) {
      bf16* rp = hbuf + (size_t)gm * 4096 + gn0;
#pragma unroll
      for (int nf = 0; nf < 4; nf++) {
        bf16x4 o;
#pragma unroll
        for (int jj = 0; jj < 4; jj++)
          o[jj] = (bf16)gelu_fast(acc[mf][nf][jj] + bv[nf][jj]);
        *(bf16x4*)(rp + nf * 16) = o;
      }
    }
  }
}

// ---------------- grouped GEMM2: y[slot] = h @ W2[e] + b2[e] (bf16) ---------
// Grid 288 = 8 xcd x 36; chunked-bijective tidx split, 4 n_tiles.
__global__ __launch_bounds__(512, 2) void gemm2_kernel(
    const bf16* __restrict__ hbuf, const bf16* __restrict__ W2t,
    const float* __restrict__ b2, bf16* __restrict__ yb,
    const int* __restrict__ meta) {
  __shared__ __align__(16) char smem[131072];
  int m_idx, n_tile;
  if (!xcd_tile(blockIdx.x, meta[10], 2, m_idx, n_tile)) return;
  int ti = meta[16 + m_idx];
  int row0 = ti & 0xFFFFF;
  int e = ti >> 20;
  int rowEnd = meta[1 + e];
  int tid = threadIdx.x;
  int w = tid >> 6, l = tid & 63;
  int wr = w >> 2, wc = w & 3;
  f32x4 acc[8][4];
#pragma unroll
  for (int a = 0; a < 8; a++)
#pragma unroll
    for (int bb = 0; bb < 4; bb++) acc[a][bb] = (f32x4){0.f, 0.f, 0.f, 0.f};
  gemm256_core(hbuf + (size_t)row0 * 4096,
               W2t + ((size_t)e * 1024 + n_tile * 256) * 4096,
               4096, 128, smem, acc, wr, wc, l);
  int mrow = l & 15, nq = (l >> 4) * 4;
  int gn0 = n_tile * 256 + wc * 64 + nq;
  f32x4 bv[4];
#pragma unroll
  for (int nf = 0; nf < 4; nf++)
    bv[nf] = *(const f32x4*)(b2 + e * 1024 + gn0 + nf * 16);
#pragma unroll
  for (int mf = 0; mf < 8; mf++) {
    int gm = row0 + wr * 128 + mf * 16 + mrow;
    if (gm < rowEnd) {
      bf16* rp = yb + (size_t)gm * 1024 + gn0;
#pragma unroll
      for (int nf = 0; nf < 4; nf++) {
        bf16x4 o;
#pragma unroll
        for (int jj = 0; jj < 4; jj++)
          o[jj] = (bf16)(acc[mf][nf][jj] + bv[nf][jj]);
        *(bf16x4*)(rp + nf * 16) = o;
      }
    }
  }
}

// ---------------- combine: out[t] = p0[t] * (y[s1] + y[s2]) -----------------
__global__ __launch_bounds__(256) void combine_kernel(
    const bf16* __restrict__ yb, const int* __restrict__ slot1,
    const int* __restrict__ slot2, const float* __restrict__ p0arr,
    float* __restrict__ out) {
  int t = blockIdx.x;
  int s1 = slot1[t], s2 = slot2[t];
  float w0 = p0arr[t];
  bf16x4 a = *(const bf16x4*)(yb + (size_t)s1 * 1024 + threadIdx.x * 4);
  bf16x4 b = *(const bf16x4*)(yb + (size_t)s2 * 1024 + threadIdx.x * 4);
  float4 o;
  o.x = w0 * ((float)a[0] + (float)b[0]);
  o.y = w0 * ((float)a[1] + (float)b[1]);
  o.z = w0 * ((float)a[2] + (float)b[2]);
  o.w = w0 * ((float)a[3] + (float)b[3]);
  *(float4*)(out + (size_t)t * 1024 + threadIdx.x * 4) = o;
}

extern "C" void kernel_launch(void* const* d_in, const int* in_sizes, int n_in,
                              void* d_out, int out_size, void* d_ws, size_t ws_size,
                              hipStream_t stream) {
  const float* x  = (const float*)d_in[0];
  const float* Wr = (const float*)d_in[1];
  const float* br = (const float*)d_in[2];
  const float* W1 = (const float*)d_in[3];
  const float* b1 = (const float*)d_in[4];
  const float* W2 = (const float*)d_in[5];
  const float* b2 = (const float*)d_in[6];
  float* out = (float*)d_out;

  char* ws = (char*)d_ws;
  int*   meta  = (int*)(ws + 0);
  int*   e01   = (int*)(ws + 4096);
  float* p0    = (float*)(ws + 36864);
  int*   slot1 = (int*)(ws + 69632);
  int*   slot2 = (int*)(ws + 102400);
  bf16*  Xg    = (bf16*)(ws + 135168);          // reused as ybuf after gemm1
  bf16*  W1t   = (bf16*)(ws + 34213888ULL);
  bf16*  W2t   = (bf16*)(ws + 101322752ULL);
  bf16*  hb    = (bf16*)(ws + 168431616ULL);
  bf16*  yb    = Xg;

  tconv_kernel<<<dim3(64, 16, 8), 256, 0, stream>>>(W1, W1t, 1024, 4096);
  tconv_kernel<<<dim3(16, 64, 8), 256, 0, stream>>>(W2, W2t, 4096, 1024);
  router_kernel<<<2048, 256, 0, stream>>>(x, Wr, br, e01, p0);
  slots_kernel<<<1, 1024, 0, stream>>>(e01, meta, slot1, slot2);
  gather_kernel<<<8192, 256, 0, stream>>>(x, slot1, slot2, Xg);
  gemm1_kernel<<<1152, 512, 0, stream>>>(Xg, W1t, b1, hb, meta);
  gemm2_kernel<<<288, 512, 0, stream>>>(hb, W2t, b2, yb, meta);
  combine_kernel<<<8192, 256, 0, stream>>>(yb, slot1, slot2, p0, out);
}

// Round 5
// 770.696 us; speedup vs baseline: 1.0284x; 1.0238x over previous
//
#include <hip/hip_runtime.h>
#include <hip/hip_bf16.h>

// MoE forward, MI355X. B=4,S=2048,H=1024,E=8,F=4096,K=2.
// router (no atomics) -> slots (scan + exact offsets + 128-row tile table) ->
// gather x->bf16 -> grouped MFMA GEMM1 (+gelu) -> grouped GEMM2 (+b2) ->
// combine (p0*(y1+y2)).
// GEMM core: BM=BN=128, BK=32, 256 thr = 4 waves (2x2), each wave 64x64
// (4x4 frags of 16x16x32). 4-buffer LDS ring (4x16KB=64KB => 2 blocks/CU),
// staged 3 K-steps ahead via global_load_lds; steady-state vmcnt(8) (never 0);
// raw s_barrier; setprio(1) around MFMA cluster. Fine tiles + dual occupancy
// fix R4's tail quantization (gemm2 was 288 coarse blocks @1/CU = 2 full
// rounds); co-resident block fills barrier-drain stalls.
// LDS pack: 2 global rows per 128B LDS row, XOR swizzle W^=(p&7)<<4; global
// source pre-applies inverse XOR (both-sides rule). Bank-conflict-free
// (R3/R4 measured SQ_LDS_BANK_CONFLICT=0 with identical math).
// Tile->block map: bijective chunked XCD split (n fastest) for L2 panel reuse.
// Expert segments UNPADDED; tiles may overhang -> mask stores at gm < rowEnd.
// Workspace (bytes), total ~305 MB:
//   [0,4096)   meta ints: off[0..8], ntiles@[10], tileInfo[<=136]@[16..]
//   [4096,..)  e01[8192] | [36864,..) p0[8192]
//   [69632,..) slot1 | [102400,..) slot2
//   [135168,..)    Xg bf16 [16640][1024] (reused as ybuf)
//   [34213888,..)  W1t bf16 [8][4096][1024]
//   [101322752,..) W2t bf16 [8][1024][4096]
//   [168431616,..) h  bf16 [16640][4096]  (ends 304746496)

typedef __bf16 bf16;
typedef __attribute__((ext_vector_type(4))) __bf16 bf16x4;
typedef __attribute__((ext_vector_type(8))) __bf16 bf16x8;
typedef __attribute__((ext_vector_type(4))) float f32x4;

#define GLD16(g, l) __builtin_amdgcn_global_load_lds( \
    (__attribute__((address_space(1))) void*)(g),      \
    (__attribute__((address_space(3))) void*)(l), 16, 0, 0)

// gelu tanh-approx == v * sigmoid(2c), 2c = 1.5957691216*v + 0.07135481627*v^3.
__device__ __forceinline__ float gelu_fast(float v) {
  float u = v * fmaf(v * v, 0.0713548162726f, 1.5957691216057308f);
  return v * __builtin_amdgcn_rcpf(1.0f + __expf(-u));
}

// ---------------- router: 1 wave per token, no atomics ----------------
__global__ __launch_bounds__(256) void router_kernel(
    const float* __restrict__ x, const float* __restrict__ Wr,
    const float* __restrict__ br, int* __restrict__ e01,
    float* __restrict__ p0arr) {
  int wv = threadIdx.x >> 6;
  int l = threadIdx.x & 63;
  int t = blockIdx.x * 4 + wv;
  float acc[8];
#pragma unroll
  for (int e = 0; e < 8; e++) acc[e] = 0.f;
  const float* xr = x + (size_t)t * 1024;
#pragma unroll
  for (int i = 0; i < 16; i++) {
    int h = l + i * 64;
    float xv = xr[h];
    const float4* w4 = (const float4*)(Wr + h * 8);
    float4 wa = w4[0], wb = w4[1];
    acc[0] += xv * wa.x; acc[1] += xv * wa.y; acc[2] += xv * wa.z; acc[3] += xv * wa.w;
    acc[4] += xv * wb.x; acc[5] += xv * wb.y; acc[6] += xv * wb.z; acc[7] += xv * wb.w;
  }
#pragma unroll
  for (int e = 0; e < 8; e++) {
    float v = acc[e];
#pragma unroll
    for (int m = 1; m < 64; m <<= 1) v += __shfl_xor(v, m, 64);
    acc[e] = v + br[e];
  }
  int i1 = 0; float m1 = acc[0];
#pragma unroll
  for (int e = 1; e < 8; e++) { if (acc[e] > m1) { m1 = acc[e]; i1 = e; } }
  int i2 = -1; float m2 = -3.4e38f;
#pragma unroll
  for (int e = 0; e < 8; e++) { if (e != i1 && acc[e] > m2) { m2 = acc[e]; i2 = e; } }
  if (l == 0) {
    e01[t] = i1 | (i2 << 8);
    p0arr[t] = 1.0f / (1.0f + __expf(m2 - m1));  // normalized top-1 prob
  }
}

// ---------------- slots: counts + exact offsets + slots + tile table --------
__global__ __launch_bounds__(1024) void slots_kernel(
    const int* __restrict__ e01, int* __restrict__ meta,
    int* __restrict__ slot1, int* __restrict__ slot2) {
  __shared__ int wtot[16];
  int tid = threadIdx.x;
  int l = tid & 63, wv = tid >> 6;
  int t0 = tid * 8;
  int i1[8], i2[8];
#pragma unroll
  for (int i = 0; i < 8; i++) {
    int ee = e01[t0 + i];
    i1[i] = ee & 255;
    i2[i] = (ee >> 8) & 255;
  }
  int offl[9];
  int running = 0;  // exact cumulative offset (identical in all threads)
  for (int e = 0; e < 8; e++) {
    offl[e] = running;
    int cthread = 0;
#pragma unroll
    for (int i = 0; i < 8; i++) cthread += (i1[i] == e) + (i2[i] == e);
    int inc = cthread;
#pragma unroll
    for (int d = 1; d < 64; d <<= 1) {
      int v = __shfl_up(inc, d, 64);
      if (l >= d) inc += v;
    }
    if (l == 63) wtot[wv] = inc;
    __syncthreads();
    int wbase = 0, total = 0;
#pragma unroll
    for (int w = 0; w < 16; w++) {
      int tw = wtot[w];
      wbase += (w < wv) ? tw : 0;
      total += tw;
    }
    int base = running + wbase + (inc - cthread);
#pragma unroll
    for (int i = 0; i < 8; i++) {
      if (i1[i] == e) { slot1[t0 + i] = base; base++; }
      if (i2[i] == e) { slot2[t0 + i] = base; base++; }
    }
    running += total;
    __syncthreads();  // protect wtot for next pass
  }
  offl[8] = running;
  if (tid == 0) {
#pragma unroll
    for (int e = 0; e < 9; e++) meta[e] = offl[e];
    int nt = 0;
    for (int e = 0; e < 8; e++)
      for (int r = offl[e]; r < offl[e + 1]; r += 128)
        meta[16 + (nt++)] = r | (e << 20);
    meta[10] = nt;
  }
}

// ---------------- gather: x -> bf16 into both expert slots ----------------
__global__ __launch_bounds__(256) void gather_kernel(
    const float* __restrict__ x, const int* __restrict__ slot1,
    const int* __restrict__ slot2, bf16* __restrict__ Xg) {
  int t = blockIdx.x;
  int s1 = slot1[t], s2 = slot2[t];
  float4 v = ((const float4*)(x + (size_t)t * 1024))[threadIdx.x];
  bf16x4 bv = { (bf16)v.x, (bf16)v.y, (bf16)v.z, (bf16)v.w };
  *(bf16x4*)(Xg + (size_t)s1 * 1024 + threadIdx.x * 4) = bv;
  *(bf16x4*)(Xg + (size_t)s2 * 1024 + threadIdx.x * 4) = bv;
}

// ---------------- transpose + fp32->bf16: in [E][R][C] -> out [E][C][R] ----
// float4 LDS fills, bf16x8 coalesced stores (16B per lane).
__global__ __launch_bounds__(256) void tconv_kernel(
    const float* __restrict__ in, bf16* __restrict__ out, int R, int C) {
  __shared__ float tile[64][65];
  size_t base = (size_t)blockIdx.z * R * C;
  int gr0 = blockIdx.y * 64, gc0 = blockIdx.x * 64;
  int tr = threadIdx.x >> 4;         // 0..15
  int tc4 = (threadIdx.x & 15) * 4;  // 0..60
#pragma unroll
  for (int i = 0; i < 4; i++) {
    int r = tr + i * 16;
    float4 v = *(const float4*)&in[base + (size_t)(gr0 + r) * C + gc0 + tc4];
    tile[r][tc4] = v.x; tile[r][tc4 + 1] = v.y;
    tile[r][tc4 + 2] = v.z; tile[r][tc4 + 3] = v.w;
  }
  __syncthreads();
  int rr0 = (threadIdx.x & 7) * 8;  // 0..56
  int cc0 = threadIdx.x >> 3;       // 0..31
#pragma unroll
  for (int i = 0; i < 2; i++) {
    int cc = cc0 + i * 32;
    bf16x8 v;
#pragma unroll
    for (int k = 0; k < 8; k++) v[k] = (bf16)tile[rr0 + k][cc];
    *(bf16x8*)&out[base + (size_t)(gc0 + cc) * R + gr0 + rr0] = v;
  }
}

// ---------- bijective chunked XCD tile map (m204 pattern) ----------
// total tiles = ntiles << nshift, flattened tidx = m_idx<<nshift | n (n fastest).
__device__ __forceinline__ bool xcd_tile(int b, int ntiles, int nshift,
                                         int& m_idx, int& n_tile) {
  int xcd = b & 7, j = b >> 3;
  int total = ntiles << nshift;
  int q = total >> 3, r = total & 7;
  int cnt = q + (xcd < r ? 1 : 0);
  if (j >= cnt) return false;
  int start = (xcd < r) ? xcd * (q + 1) : r * (q + 1) + (xcd - r) * q;
  int tidx = start + j;
  m_idx = tidx >> nshift;
  n_tile = tidx & ((1 << nshift) - 1);
  return true;
}

// ================= GEMM core (BM=BN=128, BK=32, 4-buffer ring) =============
// A [M][K], B [N][K], bf16 K-contig. Buffer (16KB): A 8KB @0, B 8KB @8192.
// Pack: global row r -> LDS row p=r>>1 (128B); within-row logical offset
// L = ((r&1)<<6)|c stored at W = L ^ ((p&7)<<4). Staging inverts the XOR on
// the global source so linear global_load_lds lands correct.
// Per K-step: {8 ds_read frags, issue 4 GLD (step t+3), barrier, lgkm0,
// setprio(1), 16 MFMA, setprio(0), vmcnt(8|4|0), barrier}. 3 steps in
// flight => vmcnt(8) steady state (12 outstanding, oldest 4 = step t+1).
__device__ __forceinline__ void gemm128_core(
    const bf16* __restrict__ Abase, const bf16* __restrict__ Bbase,
    int K, int NT, char* smem, f32x4 acc[4][4], int wr, int wc, int l) {
  int tid = threadIdx.x;
  size_t K2 = (size_t)K * 2;  // row stride bytes
  const char* src[4];
  int dst[4];
#pragma unroll
  for (int i = 0; i < 4; i++) {
    int s = (i & 1) ? (tid + 256) : tid;   // staging slot within region
    int byteoff = s * 16;                  // [0,8192)
    int p = byteoff >> 7;
    int W = byteoff & 127;
    int L = W ^ ((p & 7) << 4);
    int r = 2 * p + (L >> 6);
    int c = L & 63;
    const char* base = (const char*)((i >= 2) ? Bbase : Abase);
    src[i] = base + (size_t)r * K2 + c;
    dst[i] = ((i >= 2) ? 8192 : 0) + byteoff;
  }
  int offA[4], offB[4];
  int kc16 = (l >> 4) << 4;
#pragma unroll
  for (int t = 0; t < 4; t++) {
    int ra = wr * 64 + t * 16 + (l & 15);
    int pa = ra >> 1;
    offA[t] = (pa << 7) + ((((ra & 1) << 6) | kc16) ^ ((pa & 7) << 4));
    int rb = wc * 64 + t * 16 + (l & 15);
    int pb = rb >> 1;
    offB[t] = 8192 + (pb << 7) + ((((rb & 1) << 6) | kc16) ^ ((pb & 7) << 4));
  }
  // prologue: stage K-steps 0,1,2 into bufs 0,1,2 (12 loads in flight)
#pragma unroll
  for (int t = 0; t < 3; t++) {
    char* bu = smem + t * 16384;
#pragma unroll
    for (int i = 0; i < 4; i++) GLD16(src[i] + t * 64, bu + dst[i]);
  }
  asm volatile("s_waitcnt vmcnt(8)" ::: "memory");  // step 0 resident
  __builtin_amdgcn_s_barrier();
  for (int t = 0; t < NT; t++) {
    char* bc = smem + (t & 3) * 16384;
    char* bs = smem + ((t + 3) & 3) * 16384;
    bool st = (t + 3) < NT;
    bf16x8 af[4], bfr[4];
#pragma unroll
    for (int f = 0; f < 4; f++) bfr[f] = *(const bf16x8*)(bc + offB[f]);
#pragma unroll
    for (int f = 0; f < 4; f++) af[f] = *(const bf16x8*)(bc + offA[f]);
    if (st) {
#pragma unroll
      for (int i = 0; i < 4; i++) GLD16(src[i] + (size_t)(t + 3) * 64, bs + dst[i]);
    }
    __builtin_amdgcn_s_barrier();
    asm volatile("s_waitcnt lgkmcnt(0)" ::: "memory");
    __builtin_amdgcn_s_setprio(1);
#pragma unroll
    for (int mf = 0; mf < 4; mf++)
#pragma unroll
      for (int nf = 0; nf < 4; nf++)
        acc[mf][nf] = __builtin_amdgcn_mfma_f32_16x16x32_bf16(bfr[nf], af[mf], acc[mf][nf], 0, 0, 0);
    __builtin_amdgcn_s_setprio(0);
    if ((t + 3) < NT)      { asm volatile("s_waitcnt vmcnt(8)" ::: "memory"); }
    else if ((t + 2) < NT) { asm volatile("s_waitcnt vmcnt(4)" ::: "memory"); }
    else if ((t + 1) < NT) { asm volatile("s_waitcnt vmcnt(0)" ::: "memory"); }
    __builtin_amdgcn_s_barrier();
  }
}

// ---------------- grouped GEMM1: h = gelu(Xg @ W1[e] + b1[e]) ----------------
// Grid 4352 = 8 xcd x 544; chunked-bijective tidx split, 32 n_tiles.
__global__ __launch_bounds__(256, 2) void gemm1_kernel(
    const bf16* __restrict__ Xg, const bf16* __restrict__ W1t,
    const float* __restrict__ b1, bf16* __restrict__ hbuf,
    const int* __restrict__ meta) {
  __shared__ __align__(16) char smem[65536];
  int m_idx, n_tile;
  if (!xcd_tile(blockIdx.x, meta[10], 5, m_idx, n_tile)) return;
  int ti = meta[16 + m_idx];
  int row0 = ti & 0xFFFFF;
  int e = ti >> 20;
  int rowEnd = meta[1 + e];
  int tid = threadIdx.x;
  int w = tid >> 6, l = tid & 63;
  int wr = w >> 1, wc = w & 1;
  f32x4 acc[4][4];
#pragma unroll
  for (int a = 0; a < 4; a++)
#pragma unroll
    for (int bb = 0; bb < 4; bb++) acc[a][bb] = (f32x4){0.f, 0.f, 0.f, 0.f};
  gemm128_core(Xg + (size_t)row0 * 1024,
               W1t + ((size_t)e * 4096 + n_tile * 128) * 1024,
               1024, 32, smem, acc, wr, wc, l);
  int mrow = l & 15, nq = (l >> 4) * 4;
  int gn0 = n_tile * 128 + wc * 64 + nq;
  f32x4 bv[4];
#pragma unroll
  for (int nf = 0; nf < 4; nf++)
    bv[nf] = *(const f32x4*)(b1 + e * 4096 + gn0 + nf * 16);
#pragma unroll
  for (int mf = 0; mf < 4; mf++) {
    int gm = row0 + wr * 64 + mf * 16 + mrow;
    if (gm < rowEnd) {
      bf16* rp = hbuf + (size_t)gm * 4096 + gn0;
#pragma unroll
      for (int nf = 0; nf < 4; nf++) {
        bf16x4 o;
#pragma unroll
        for (int jj = 0; jj < 4; jj++)
          o[jj] = (bf16)gelu_fast(acc[mf][nf][jj] + bv[nf][jj]);
        *(bf16x4*)(rp + nf * 16) = o;
      }
    }
  }
}

// ---------------- grouped GEMM2: y[slot] = h @ W2[e] + b2[e] (bf16) ---------
// Grid 1088 = 8 xcd x 136; chunked-bijective tidx split, 8 n_tiles.
__global__ __launch_bounds__(256, 2) void gemm2_kernel(
    const bf16* __restrict__ hbuf, const bf16* __restrict__ W2t,
    const float* __restrict__ b2, bf16* __restrict__ yb,
    const int* __restrict__ meta) {
  __shared__ __align__(16) char smem[65536];
  int m_idx, n_tile;
  if (!xcd_tile(blockIdx.x, meta[10], 3, m_idx, n_tile)) return;
  int ti = meta[16 + m_idx];
  int row0 = ti & 0xFFFFF;
  int e = ti >> 20;
  int rowEnd = meta[1 + e];
  int tid = threadIdx.x;
  int w = tid >> 6, l = tid & 63;
  int wr = w >> 1, wc = w & 1;
  f32x4 acc[4][4];
#pragma unroll
  for (int a = 0; a < 4; a++)
#pragma unroll
    for (int bb = 0; bb < 4; bb++) acc[a][bb] = (f32x4){0.f, 0.f, 0.f, 0.f};
  gemm128_core(hbuf + (size_t)row0 * 4096,
               W2t + ((size_t)e * 1024 + n_tile * 128) * 4096,
               4096, 128, smem, acc, wr, wc, l);
  int mrow = l & 15, nq = (l >> 4) * 4;
  int gn0 = n_tile * 128 + wc * 64 + nq;
  f32x4 bv[4];
#pragma unroll
  for (int nf = 0; nf < 4; nf++)
    bv[nf] = *(const f32x4*)(b2 + e * 1024 + gn0 + nf * 16);
#pragma unroll
  for (int mf = 0; mf < 4; mf++) {
    int gm = row0 + wr * 64 + mf * 16 + mrow;
    if (gm < rowEnd) {
      bf16* rp = yb + (size_t)gm * 1024 + gn0;
#pragma unroll
      for (int nf = 0; nf < 4; nf++) {
        bf16x4 o;
#pragma unroll
        for (int jj = 0; jj < 4; jj++)
          o[jj] = (bf16)(acc[mf][nf][jj] + bv[nf][jj]);
        *(bf16x4*)(rp + nf * 16) = o;
      }
    }
  }
}

// ---------------- combine: out[t] = p0[t] * (y[s1] + y[s2]) -----------------
__global__ __launch_bounds__(256) void combine_kernel(
    const bf16* __restrict__ yb, const int* __restrict__ slot1,
    const int* __restrict__ slot2, const float* __restrict__ p0arr,
    float* __restrict__ out) {
  int t = blockIdx.x;
  int s1 = slot1[t], s2 = slot2[t];
  float w0 = p0arr[t];
  bf16x4 a = *(const bf16x4*)(yb + (size_t)s1 * 1024 + threadIdx.x * 4);
  bf16x4 b = *(const bf16x4*)(yb + (size_t)s2 * 1024 + threadIdx.x * 4);
  float4 o;
  o.x = w0 * ((float)a[0] + (float)b[0]);
  o.y = w0 * ((float)a[1] + (float)b[1]);
  o.z = w0 * ((float)a[2] + (float)b[2]);
  o.w = w0 * ((float)a[3] + (float)b[3]);
  *(float4*)(out + (size_t)t * 1024 + threadIdx.x * 4) = o;
}

extern "C" void kernel_launch(void* const* d_in, const int* in_sizes, int n_in,
                              void* d_out, int out_size, void* d_ws, size_t ws_size,
                              hipStream_t stream) {
  const float* x  = (const float*)d_in[0];
  const float* Wr = (const float*)d_in[1];
  const float* br = (const float*)d_in[2];
  const float* W1 = (const float*)d_in[3];
  const float* b1 = (const float*)d_in[4];
  const float* W2 = (const float*)d_in[5];
  const float* b2 = (const float*)d_in[6];
  float* out = (float*)d_out;

  char* ws = (char*)d_ws;
  int*   meta  = (int*)(ws + 0);
  int*   e01   = (int*)(ws + 4096);
  float* p0    = (float*)(ws + 36864);
  int*   slot1 = (int*)(ws + 69632);
  int*   slot2 = (int*)(ws + 102400);
  bf16*  Xg    = (bf16*)(ws + 135168);          // reused as ybuf after gemm1
  bf16*  W1t   = (bf16*)(ws + 34213888ULL);
  bf16*  W2t   = (bf16*)(ws + 101322752ULL);
  bf16*  hb    = (bf16*)(ws + 168431616ULL);
  bf16*  yb    = Xg;

  tconv_kernel<<<dim3(64, 16, 8), 256, 0, stream>>>(W1, W1t, 1024, 4096);
  tconv_kernel<<<dim3(16, 64, 8), 256, 0, stream>>>(W2, W2t, 4096, 1024);
  router_kernel<<<2048, 256, 0, stream>>>(x, Wr, br, e01, p0);
  slots_kernel<<<1, 1024, 0, stream>>>(e01, meta, slot1, slot2);
  gather_kernel<<<8192, 256, 0, stream>>>(x, slot1, slot2, Xg);
  gemm1_kernel<<<4352, 256, 0, stream>>>(Xg, W1t, b1, hb, meta);
  gemm2_kernel<<<1088, 256, 0, stream>>>(hb, W2t, b2, yb, meta);
  combine_kernel<<<8192, 256, 0, stream>>>(yb, slot1, slot2, p0, out);
}

// Round 7
// 734.066 us; speedup vs baseline: 1.0797x; 1.0499x over previous
//
#include <hip/hip_runtime.h>
#include <hip/hip_bf16.h>

// MoE forward, MI355X. B=4,S=2048,H=1024,E=8,F=4096,K=2.
// router (no atomics) -> slots (scan + exact offsets + 256-row tile table) ->
// prep {gather x->bf16 || W1/W2 transpose+bf16} -> grouped MFMA GEMM1 (+gelu)
// -> grouped GEMM2 (+b2) -> combine (p0*(y1+y2)).
// GEMM core: BM=256(A) x BN=128(B), BK=32, 256 thr = 4 waves (2Mx2N), each
// wave 128x64 (8x4 frags of 16x16x32) => m201 wave shape, 0.023 LDS B/FLOP.
// 3-buffer LDS ring (3x24KB=72KB => 2 blocks/CU): geometry AND packing.
// (R5 showed 128^2/64x64-wave tops at ~640 TF even well-packed; R4 showed
// 256^2 core = 1.13 PF/round but tail-quantized at 1 block/CU.)
// Staged 2 K-steps ahead via global_load_lds (6 loads/step: 4A+2B);
// steady-state s_waitcnt vmcnt(6) (never 0); raw s_barrier; setprio(1)
// around each 16-MFMA cluster; 2 phases per K-step.
// LDS pack: 2 global rows per 128B LDS row, XOR swizzle W^=(p&7)<<4; global
// source pre-applies inverse XOR (both-sides rule; SQ_LDS_BANK_CONFLICT=0
// measured R3-R5 with identical math).
// Tile->block map: bijective chunked XCD split (n fastest) for L2 panel reuse.
// Expert segments UNPADDED; tiles may overhang -> mask stores at gm < rowEnd.
// (R6 bench was an infra failure: "container failed twice", no counters.
//  Code audited for OOB/deadlock/graph-capture violations; resubmitted
//  unchanged for a clean A/B vs R5.)
// Workspace (bytes), total ~305 MB:
//   [0,4096)   meta ints: off[0..8], ntiles@[10], tileInfo[<=72]@[16..]
//   [4096,..)  e01[8192] | [36864,..) p0[8192]
//   [69632,..) slot1 | [102400,..) slot2
//   [135168,..)    Xg bf16 [16640][1024] (reused as ybuf)
//   [34213888,..)  W1t bf16 [8][4096][1024]
//   [101322752,..) W2t bf16 [8][1024][4096]
//   [168431616,..) h  bf16 [16640][4096]  (ends 304746496)

typedef __bf16 bf16;
typedef __attribute__((ext_vector_type(4))) __bf16 bf16x4;
typedef __attribute__((ext_vector_type(8))) __bf16 bf16x8;
typedef __attribute__((ext_vector_type(4))) float f32x4;

#define GLD16(g, l) __builtin_amdgcn_global_load_lds( \
    (__attribute__((address_space(1))) void*)(g),      \
    (__attribute__((address_space(3))) void*)(l), 16, 0, 0)

// gelu tanh-approx == v * sigmoid(2c), 2c = 1.5957691216*v + 0.07135481627*v^3.
__device__ __forceinline__ float gelu_fast(float v) {
  float u = v * fmaf(v * v, 0.0713548162726f, 1.5957691216057308f);
  return v * __builtin_amdgcn_rcpf(1.0f + __expf(-u));
}

// ---------------- router: 1 wave per token, no atomics ----------------
__global__ __launch_bounds__(256) void router_kernel(
    const float* __restrict__ x, const float* __restrict__ Wr,
    const float* __restrict__ br, int* __restrict__ e01,
    float* __restrict__ p0arr) {
  int wv = threadIdx.x >> 6;
  int l = threadIdx.x & 63;
  int t = blockIdx.x * 4 + wv;
  float acc[8];
#pragma unroll
  for (int e = 0; e < 8; e++) acc[e] = 0.f;
  const float* xr = x + (size_t)t * 1024;
#pragma unroll
  for (int i = 0; i < 16; i++) {
    int h = l + i * 64;
    float xv = xr[h];
    const float4* w4 = (const float4*)(Wr + h * 8);
    float4 wa = w4[0], wb = w4[1];
    acc[0] += xv * wa.x; acc[1] += xv * wa.y; acc[2] += xv * wa.z; acc[3] += xv * wa.w;
    acc[4] += xv * wb.x; acc[5] += xv * wb.y; acc[6] += xv * wb.z; acc[7] += xv * wb.w;
  }
#pragma unroll
  for (int e = 0; e < 8; e++) {
    float v = acc[e];
#pragma unroll
    for (int m = 1; m < 64; m <<= 1) v += __shfl_xor(v, m, 64);
    acc[e] = v + br[e];
  }
  int i1 = 0; float m1 = acc[0];
#pragma unroll
  for (int e = 1; e < 8; e++) { if (acc[e] > m1) { m1 = acc[e]; i1 = e; } }
  int i2 = -1; float m2 = -3.4e38f;
#pragma unroll
  for (int e = 0; e < 8; e++) { if (e != i1 && acc[e] > m2) { m2 = acc[e]; i2 = e; } }
  if (l == 0) {
    e01[t] = i1 | (i2 << 8);
    p0arr[t] = 1.0f / (1.0f + __expf(m2 - m1));  // normalized top-1 prob
  }
}

// ---------------- slots: counts + exact offsets + slots + tile table --------
__global__ __launch_bounds__(1024) void slots_kernel(
    const int* __restrict__ e01, int* __restrict__ meta,
    int* __restrict__ slot1, int* __restrict__ slot2) {
  __shared__ int wtot[16];
  int tid = threadIdx.x;
  int l = tid & 63, wv = tid >> 6;
  int t0 = tid * 8;
  int i1[8], i2[8];
#pragma unroll
  for (int i = 0; i < 8; i++) {
    int ee = e01[t0 + i];
    i1[i] = ee & 255;
    i2[i] = (ee >> 8) & 255;
  }
  int offl[9];
  int running = 0;  // exact cumulative offset (identical in all threads)
  for (int e = 0; e < 8; e++) {
    offl[e] = running;
    int cthread = 0;
#pragma unroll
    for (int i = 0; i < 8; i++) cthread += (i1[i] == e) + (i2[i] == e);
    int inc = cthread;
#pragma unroll
    for (int d = 1; d < 64; d <<= 1) {
      int v = __shfl_up(inc, d, 64);
      if (l >= d) inc += v;
    }
    if (l == 63) wtot[wv] = inc;
    __syncthreads();
    int wbase = 0, total = 0;
#pragma unroll
    for (int w = 0; w < 16; w++) {
      int tw = wtot[w];
      wbase += (w < wv) ? tw : 0;
      total += tw;
    }
    int base = running + wbase + (inc - cthread);
#pragma unroll
    for (int i = 0; i < 8; i++) {
      if (i1[i] == e) { slot1[t0 + i] = base; base++; }
      if (i2[i] == e) { slot2[t0 + i] = base; base++; }
    }
    running += total;
    __syncthreads();  // protect wtot for next pass
  }
  offl[8] = running;
  if (tid == 0) {
#pragma unroll
    for (int e = 0; e < 9; e++) meta[e] = offl[e];
    int nt = 0;
    for (int e = 0; e < 8; e++)
      for (int r = offl[e]; r < offl[e + 1]; r += 256)
        meta[16 + (nt++)] = r | (e << 20);
    meta[10] = nt;
  }
}

// ---------------- prep: gather (8192) || tconv W1 (8192) || tconv W2 (8192) -
// Merged: gather hides under the weight transposes; saves 2 launch gaps.
__global__ __launch_bounds__(256) void prep_kernel(
    const float* __restrict__ x, const int* __restrict__ slot1,
    const int* __restrict__ slot2, bf16* __restrict__ Xg,
    const float* __restrict__ W1, bf16* __restrict__ W1t,
    const float* __restrict__ W2, bf16* __restrict__ W2t) {
  __shared__ float tile[64][65];
  int b = blockIdx.x;
  if (b < 8192) {  // gather: x -> bf16 into both expert slots
    int t = b;
    int s1 = slot1[t], s2 = slot2[t];
    float4 v = ((const float4*)(x + (size_t)t * 1024))[threadIdx.x];
    bf16x4 bv = { (bf16)v.x, (bf16)v.y, (bf16)v.z, (bf16)v.w };
    *(bf16x4*)(Xg + (size_t)s1 * 1024 + threadIdx.x * 4) = bv;
    *(bf16x4*)(Xg + (size_t)s2 * 1024 + threadIdx.x * 4) = bv;
    return;
  }
  // transpose + fp32->bf16: in [E][R][C] -> out [E][C][R]
  const float* in; bf16* outp; int R, C, bx, by, bz;
  if (b < 16384) {
    int b2 = b - 8192;
    in = W1; outp = W1t; R = 1024; C = 4096;
    bx = b2 & 63; by = (b2 >> 6) & 15; bz = b2 >> 10;
  } else {
    int b2 = b - 16384;
    in = W2; outp = W2t; R = 4096; C = 1024;
    bx = b2 & 15; by = (b2 >> 4) & 63; bz = b2 >> 10;
  }
  size_t base = (size_t)bz * R * C;
  int gr0 = by * 64, gc0 = bx * 64;
  int tr = threadIdx.x >> 4;         // 0..15
  int tc4 = (threadIdx.x & 15) * 4;  // 0..60
#pragma unroll
  for (int i = 0; i < 4; i++) {
    int r = tr + i * 16;
    float4 v = *(const float4*)&in[base + (size_t)(gr0 + r) * C + gc0 + tc4];
    tile[r][tc4] = v.x; tile[r][tc4 + 1] = v.y;
    tile[r][tc4 + 2] = v.z; tile[r][tc4 + 3] = v.w;
  }
  __syncthreads();
  int rr0 = (threadIdx.x & 7) * 8;  // 0..56
  int cc0 = threadIdx.x >> 3;       // 0..31
#pragma unroll
  for (int i = 0; i < 2; i++) {
    int cc = cc0 + i * 32;
    bf16x8 v;
#pragma unroll
    for (int k = 0; k < 8; k++) v[k] = (bf16)tile[rr0 + k][cc];
    *(bf16x8*)&outp[base + (size_t)(gc0 + cc) * R + gr0 + rr0] = v;
  }
}

// ---------- bijective chunked XCD tile map (m204 pattern) ----------
// total tiles = ntiles << nshift, flattened tidx = m_idx<<nshift | n (n fastest).
__device__ __forceinline__ bool xcd_tile(int b, int ntiles, int nshift,
                                         int& m_idx, int& n_tile) {
  int xcd = b & 7, j = b >> 3;
  int total = ntiles << nshift;
  int q = total >> 3, r = total & 7;
  int cnt = q + (xcd < r ? 1 : 0);
  if (j >= cnt) return false;
  int start = (xcd < r) ? xcd * (q + 1) : r * (q + 1) + (xcd - r) * q;
  int tidx = start + j;
  m_idx = tidx >> nshift;
  n_tile = tidx & ((1 << nshift) - 1);
  return true;
}

// ============ GEMM core (BM=256, BN=128, BK=32, 3-buffer ring) =============
// A [M][K], B [N][K], bf16 K-contig. Buffer (24KB): A 16KB @0, B 8KB @16384.
// Pack: global row r -> LDS row p=r>>1 (128B); within-row logical offset
// L = ((r&1)<<6)|c stored at W = L ^ ((p&7)<<4). Staging inverts the XOR on
// the global source so linear global_load_lds lands correct.
// Per K-step: ph0 {read 4 B-frags + 4 A-frags, issue 4 A-GLD (t+2), barrier,
// lgkm0, setprio(1), 16 MFMA, setprio(0), barrier}; ph1 {read 4 A-frags,
// issue 2 B-GLD (t+2), barrier, lgkm0, 16 MFMA, vmcnt(6|0), barrier}.
// 2 steps staged ahead, 6 loads/step => vmcnt(6) steady state (never 0).
__device__ __forceinline__ void gemm_core(
    const bf16* __restrict__ Abase, const bf16* __restrict__ Bbase,
    int K, int NT, char* smem, f32x4 acc[8][4], int wr, int wc, int l) {
  int tid = threadIdx.x;
  size_t K2 = (size_t)K * 2;  // row stride bytes
  const char* srcA[4]; const char* srcB[2];
  int dstA[4], dstB[2];
#pragma unroll
  for (int i = 0; i < 4; i++) {
    int byteoff = (tid + i * 256) * 16;  // [0,16384)
    int p = byteoff >> 7, W = byteoff & 127;
    int L = W ^ ((p & 7) << 4);
    int r = 2 * p + (L >> 6), c = L & 63;
    srcA[i] = (const char*)Abase + (size_t)r * K2 + c;
    dstA[i] = byteoff;
  }
#pragma unroll
  for (int i = 0; i < 2; i++) {
    int byteoff = (tid + i * 256) * 16;  // [0,8192)
    int p = byteoff >> 7, W = byteoff & 127;
    int L = W ^ ((p & 7) << 4);
    int r = 2 * p + (L >> 6), c = L & 63;
    srcB[i] = (const char*)Bbase + (size_t)r * K2 + c;
    dstB[i] = 16384 + byteoff;
  }
  int offA[8], offB[4];
  int kc16 = (l >> 4) << 4;
#pragma unroll
  for (int mf = 0; mf < 8; mf++) {
    int r = wr * 128 + mf * 16 + (l & 15);
    int p = r >> 1;
    offA[mf] = (p << 7) + ((((r & 1) << 6) | kc16) ^ ((p & 7) << 4));
  }
#pragma unroll
  for (int nf = 0; nf < 4; nf++) {
    int r = wc * 64 + nf * 16 + (l & 15);
    int p = r >> 1;
    offB[nf] = 16384 + (p << 7) + ((((r & 1) << 6) | kc16) ^ ((p & 7) << 4));
  }
  // prologue: stage K-steps 0,1 (12 loads in flight)
#pragma unroll
  for (int t = 0; t < 2; t++) {
    char* bu = smem + t * 24576;
#pragma unroll
    for (int i = 0; i < 4; i++) GLD16(srcA[i] + t * 64, bu + dstA[i]);
#pragma unroll
    for (int i = 0; i < 2; i++) GLD16(srcB[i] + t * 64, bu + dstB[i]);
  }
  asm volatile("s_waitcnt vmcnt(6)" ::: "memory");  // step 0 resident
  __builtin_amdgcn_s_barrier();
  char* bc = smem;                // compute buffer (step t)
  char* bs = smem + 2 * 24576;    // stage target (step t+2)
  for (int t = 0; t < NT; t++) {
    bool st = (t + 2) < NT;
    bf16x8 bfr[4], af[4];
    // ---- phase 0 ----
#pragma unroll
    for (int nf = 0; nf < 4; nf++) bfr[nf] = *(const bf16x8*)(bc + offB[nf]);
#pragma unroll
    for (int mf = 0; mf < 4; mf++) af[mf] = *(const bf16x8*)(bc + offA[mf]);
    if (st) {
#pragma unroll
      for (int i = 0; i < 4; i++)
        GLD16(srcA[i] + (size_t)(t + 2) * 64, bs + dstA[i]);
    }
    __builtin_amdgcn_s_barrier();
    asm volatile("s_waitcnt lgkmcnt(0)" ::: "memory");
    __builtin_amdgcn_s_setprio(1);
#pragma unroll
    for (int mf = 0; mf < 4; mf++)
#pragma unroll
      for (int nf = 0; nf < 4; nf++)
        acc[mf][nf] = __builtin_amdgcn_mfma_f32_16x16x32_bf16(bfr[nf], af[mf], acc[mf][nf], 0, 0, 0);
    __builtin_amdgcn_s_setprio(0);
    __builtin_amdgcn_s_barrier();
    // ---- phase 1 ----
#pragma unroll
    for (int mf = 0; mf < 4; mf++) af[mf] = *(const bf16x8*)(bc + offA[mf + 4]);
    if (st) {
#pragma unroll
      for (int i = 0; i < 2; i++)
        GLD16(srcB[i] + (size_t)(t + 2) * 64, bs + dstB[i]);
    }
    __builtin_amdgcn_s_barrier();
    asm volatile("s_waitcnt lgkmcnt(0)" ::: "memory");
    __builtin_amdgcn_s_setprio(1);
#pragma unroll
    for (int mf = 0; mf < 4; mf++)
#pragma unroll
      for (int nf = 0; nf < 4; nf++)
        acc[mf + 4][nf] = __builtin_amdgcn_mfma_f32_16x16x32_bf16(bfr[nf], af[mf], acc[mf + 4][nf], 0, 0, 0);
    __builtin_amdgcn_s_setprio(0);
    if (st)              { asm volatile("s_waitcnt vmcnt(6)" ::: "memory"); }
    else if (t + 1 < NT) { asm volatile("s_waitcnt vmcnt(0)" ::: "memory"); }
    __builtin_amdgcn_s_barrier();
    bc += 24576; if (bc == smem + 73728) bc = smem;
    bs += 24576; if (bs == smem + 73728) bs = smem;
  }
}

// ---------------- grouped GEMM1: h = gelu(Xg @ W1[e] + b1[e]) ----------------
// Grid 2304 = 8 xcd x 288; <=72 m-tiles (256 rows) x 32 n_tiles (128 cols).
__global__ __launch_bounds__(256, 2) void gemm1_kernel(
    const bf16* __restrict__ Xg, const bf16* __restrict__ W1t,
    const float* __restrict__ b1, bf16* __restrict__ hbuf,
    const int* __restrict__ meta) {
  __shared__ __align__(16) char smem[73728];
  int m_idx, n_tile;
  if (!xcd_tile(blockIdx.x, meta[10], 5, m_idx, n_tile)) return;
  int ti = meta[16 + m_idx];
  int row0 = ti & 0xFFFFF;
  int e = ti >> 20;
  int rowEnd = meta[1 + e];
  int tid = threadIdx.x;
  int w = tid >> 6, l = tid & 63;
  int wr = w >> 1, wc = w & 1;
  f32x4 acc[8][4];
#pragma unroll
  for (int a = 0; a < 8; a++)
#pragma unroll
    for (int bb = 0; bb < 4; bb++) acc[a][bb] = (f32x4){0.f, 0.f, 0.f, 0.f};
  gemm_core(Xg + (size_t)row0 * 1024,
            W1t + ((size_t)e * 4096 + n_tile * 128) * 1024,
            1024, 32, smem, acc, wr, wc, l);
  int mrow = l & 15, nq = (l >> 4) * 4;
  int gn0 = n_tile * 128 + wc * 64 + nq;
  f32x4 bv[4];
#pragma unroll
  for (int nf = 0; nf < 4; nf++)
    bv[nf] = *(const f32x4*)(b1 + e * 4096 + gn0 + nf * 16);
#pragma unroll
  for (int mf = 0; mf < 8; mf++) {
    int gm = row0 + wr * 128 + mf * 16 + mrow;
    if (gm < rowEnd) {
      bf16* rp = hbuf + (size_t)gm * 4096 + gn0;
#pragma unroll
      for (int nf = 0; nf < 4; nf++) {
        bf16x4 o;
#pragma unroll
        for (int jj = 0; jj < 4; jj++)
          o[jj] = (bf16)gelu_fast(acc[mf][nf][jj] + bv[nf][jj]);
        *(bf16x4*)(rp + nf * 16) = o;
      }
    }
  }
}

// ---------------- grouped GEMM2: y[slot] = h @ W2[e] + b2[e] (bf16) ---------
// Grid 576 = 8 xcd x 72; <=72 m-tiles x 8 n_tiles.
__global__ __launch_bounds__(256, 2) void gemm2_kernel(
    const bf16* __restrict__ hbuf, const bf16* __restrict__ W2t,
    const float* __restrict__ b2, bf16* __restrict__ yb,
    const int* __restrict__ meta) {
  __shared__ __align__(16) char smem[73728];
  int m_idx, n_tile;
  if (!xcd_tile(blockIdx.x, meta[10], 3, m_idx, n_tile)) return;
  int ti = meta[16 + m_idx];
  int row0 = ti & 0xFFFFF;
  int e = ti >> 20;
  int rowEnd = meta[1 + e];
  int tid = threadIdx.x;
  int w = tid >> 6, l = tid & 63;
  int wr = w >> 1, wc = w & 1;
  f32x4 acc[8][4];
#pragma unroll
  for (int a = 0; a < 8; a++)
#pragma unroll
    for (int bb = 0; bb < 4; bb++) acc[a][bb] = (f32x4){0.f, 0.f, 0.f, 0.f};
  gemm_core(hbuf + (size_t)row0 * 4096,
            W2t + ((size_t)e * 1024 + n_tile * 128) * 4096,
            4096, 128, smem, acc, wr, wc, l);
  int mrow = l & 15, nq = (l >> 4) * 4;
  int gn0 = n_tile * 128 + wc * 64 + nq;
  f32x4 bv[4];
#pragma unroll
  for (int nf = 0; nf < 4; nf++)
    bv[nf] = *(const f32x4*)(b2 + e * 1024 + gn0 + nf * 16);
#pragma unroll
  for (int mf = 0; mf < 8; mf++) {
    int gm = row0 + wr * 128 + mf * 16 + mrow;
    if (gm < rowEnd) {
      bf16* rp = yb + (size_t)gm * 1024 + gn0;
#pragma unroll
      for (int nf = 0; nf < 4; nf++) {
        bf16x4 o;
#pragma unroll
        for (int jj = 0; jj < 4; jj++)
          o[jj] = (bf16)(acc[mf][nf][jj] + bv[nf][jj]);
        *(bf16x4*)(rp + nf * 16) = o;
      }
    }
  }
}

// ---------------- combine: out[t] = p0[t] * (y[s1] + y[s2]) -----------------
__global__ __launch_bounds__(256) void combine_kernel(
    const bf16* __restrict__ yb, const int* __restrict__ slot1,
    const int* __restrict__ slot2, const float* __restrict__ p0arr,
    float* __restrict__ out) {
  int t = blockIdx.x;
  int s1 = slot1[t], s2 = slot2[t];
  float w0 = p0arr[t];
  bf16x4 a = *(const bf16x4*)(yb + (size_t)s1 * 1024 + threadIdx.x * 4);
  bf16x4 b = *(const bf16x4*)(yb + (size_t)s2 * 1024 + threadIdx.x * 4);
  float4 o;
  o.x = w0 * ((float)a[0] + (float)b[0]);
  o.y = w0 * ((float)a[1] + (float)b[1]);
  o.z = w0 * ((float)a[2] + (float)b[2]);
  o.w = w0 * ((float)a[3] + (float)b[3]);
  *(float4*)(out + (size_t)t * 1024 + threadIdx.x * 4) = o;
}

extern "C" void kernel_launch(void* const* d_in, const int* in_sizes, int n_in,
                              void* d_out, int out_size, void* d_ws, size_t ws_size,
                              hipStream_t stream) {
  const float* x  = (const float*)d_in[0];
  const float* Wr = (const float*)d_in[1];
  const float* br = (const float*)d_in[2];
  const float* W1 = (const float*)d_in[3];
  const float* b1 = (const float*)d_in[4];
  const float* W2 = (const float*)d_in[5];
  const float* b2 = (const float*)d_in[6];
  float* out = (float*)d_out;

  char* ws = (char*)d_ws;
  int*   meta  = (int*)(ws + 0);
  int*   e01   = (int*)(ws + 4096);
  float* p0    = (float*)(ws + 36864);
  int*   slot1 = (int*)(ws + 69632);
  int*   slot2 = (int*)(ws + 102400);
  bf16*  Xg    = (bf16*)(ws + 135168);          // reused as ybuf after gemm1
  bf16*  W1t   = (bf16*)(ws + 34213888ULL);
  bf16*  W2t   = (bf16*)(ws + 101322752ULL);
  bf16*  hb    = (bf16*)(ws + 168431616ULL);
  bf16*  yb    = Xg;

  router_kernel<<<2048, 256, 0, stream>>>(x, Wr, br, e01, p0);
  slots_kernel<<<1, 1024, 0, stream>>>(e01, meta, slot1, slot2);
  prep_kernel<<<24576, 256, 0, stream>>>(x, slot1, slot2, Xg, W1, W1t, W2, W2t);
  gemm1_kernel<<<2304, 256, 0, stream>>>(Xg, W1t, b1, hb, meta);
  gemm2_kernel<<<576, 256, 0, stream>>>(hb, W2t, b2, yb, meta);
  combine_kernel<<<8192, 256, 0, stream>>>(yb, slot1, slot2, p0, out);
}